// Round 6
// baseline (213.020 us; speedup 1.0000x reference)
//
#include <hip/hip_runtime.h>
#include <hip/hip_bf16.h>
#include <math.h>

#define BB 16
#define CC 512
#define NH 8
#define HD 64
#define NN 1024   // H*W
#define THREEC 1536

// Q pre-scale: (1/sqrt(64)) * log2(e)  -> softmax via raw v_exp_f32 (2^x)
#define QSCALE 0.18033688f

typedef __attribute__((ext_vector_type(8))) short bf16x8;
typedef __attribute__((ext_vector_type(4))) float f32x4;
typedef __attribute__((ext_vector_type(16))) float f32x16;

#if __has_builtin(__builtin_amdgcn_exp2f)
#define EXP2F __builtin_amdgcn_exp2f
#else
#define EXP2F exp2f
#endif

// workspace byte offsets
#define XT_OFF 0u           // bf16 x^T [b][n][c]          (16.78 MB)
#define WQ_OFF 16777216u    // bf16 w_qkv [1536][512]      (1.57 MB)
#define WP_OFF 18350080u    // bf16 w_proj [512][512]      (0.52 MB)
#define QB_OFF 18874368u    // bf16 Q (scaled QSCALE) [bh][n][d]
#define KB_OFF 35651584u    // bf16 K [bh][n][d]
#define VT_OFF 52428800u    // bf16 V^T [bh][d][n]
#define AB_OFF 69206016u    // bf16 attn-out [b][n][c]
// end 85983232 (82 MiB)

static __device__ inline unsigned short f2bf(float f) {
  union { float f; unsigned u; } v; v.f = f;
  unsigned r = v.u + 0x7fffu + ((v.u >> 16) & 1u);
  return (unsigned short)(r >> 16);
}

// pack two f32 -> two bf16 in a u32 (lo = a, hi = b)
static __device__ inline unsigned pk2bf(float a, float b) {
#if defined(__AMDGCN__) && __has_builtin(__builtin_amdgcn_cvt_pk_bf16_f32)
  typedef __attribute__((ext_vector_type(2))) __bf16 bfp2;
  union { bfp2 v; unsigned u; } z;
  z.v = __builtin_amdgcn_cvt_pk_bf16_f32(a, b);
  return z.u;
#else
  return (unsigned)f2bf(a) | ((unsigned)f2bf(b) << 16);
#endif
}

static __device__ inline void gld_lds16(const unsigned short* g, unsigned short* l) {
  __builtin_amdgcn_global_load_lds(
      (const __attribute__((address_space(1))) unsigned int*)g,
      (__attribute__((address_space(3))) unsigned int*)l, 16, 0, 0);
}

// ---------------------------------------------------------------------------
// prep_w: convert w_qkv (786432) + w_proj (262144) fp32 -> bf16
// ---------------------------------------------------------------------------
__global__ __launch_bounds__(256) void prep_w(const float* __restrict__ wqkv,
                                              const float* __restrict__ wproj,
                                              unsigned short* __restrict__ dq,
                                              unsigned short* __restrict__ dp) {
  const size_t i8 = ((size_t)blockIdx.x * 256 + threadIdx.x) * 8;
  const float* src;
  unsigned short* dst;
  if (i8 < 786432u) { src = wqkv + i8; dst = dq + i8; }
  else              { src = wproj + (i8 - 786432u); dst = dp + (i8 - 786432u); }
  float4 a = *(const float4*)src;
  float4 b = *(const float4*)(src + 4);
  unsigned short pk[8] = {f2bf(a.x), f2bf(a.y), f2bf(a.z), f2bf(a.w),
                          f2bf(b.x), f2bf(b.y), f2bf(b.z), f2bf(b.w)};
  *(uint4*)dst = *(const uint4*)pk;
}

// ---------------------------------------------------------------------------
// prep_xT: x [b][c][n] fp32 -> xT [b][n][c] bf16. 64x64 LDS tile transpose.
// ---------------------------------------------------------------------------
__global__ __launch_bounds__(256) void prep_xT(const float* __restrict__ x,
                                               unsigned short* __restrict__ xT) {
  const int b  = blockIdx.z;
  const int c0 = blockIdx.y * 64;
  const int n0 = blockIdx.x * 64;
  __shared__ float tile[64][65];
  const int t  = threadIdx.x;
  const int cl = t >> 4, n4 = (t & 15) * 4;
#pragma unroll
  for (int r = 0; r < 4; ++r) {
    float4 v = *(const float4*)&x[((size_t)b * CC + c0 + cl + 16 * r) * NN + n0 + n4];
    *(float4*)&tile[cl + 16 * r][n4] = v;
  }
  __syncthreads();
  const int nl = t >> 4, c4 = (t & 15) * 4;
#pragma unroll
  for (int r = 0; r < 4; ++r) {
    ushort4 p;
    p.x = f2bf(tile[c4 + 0][nl + 16 * r]);
    p.y = f2bf(tile[c4 + 1][nl + 16 * r]);
    p.z = f2bf(tile[c4 + 2][nl + 16 * r]);
    p.w = f2bf(tile[c4 + 3][nl + 16 * r]);
    *(ushort4*)&xT[((size_t)b * NN + n0 + nl + 16 * r) * CC + c0 + c4] = p;
  }
}

// ---------------------------------------------------------------------------
// qkv_mfma: [1536x512] @ [512x1024] per batch, bf16 MFMA, 128x128 tile BK=64.
// ---------------------------------------------------------------------------
__global__ __launch_bounds__(256) void qkv_mfma(const unsigned short* __restrict__ wq,
                                                const unsigned short* __restrict__ xT,
                                                unsigned short* __restrict__ qb,
                                                unsigned short* __restrict__ kb_,
                                                unsigned short* __restrict__ vt) {
  const int b  = blockIdx.z;
  const int o0 = blockIdx.y * 128;
  const int n0 = blockIdx.x * 128;
  const int t  = threadIdx.x;
  const int w    = t >> 6;
  const int lane = t & 63;
  const int quad = lane >> 4;
  const int l16  = lane & 15;
  const int m_off = (w >> 1) * 64;
  const int n_off = (w & 1) * 64;

  __shared__ unsigned short sm[17408];
  unsigned short* As = sm;
  unsigned short* Bs = sm + 8192;

  const int which = o0 >> 9;       // 0=Q,1=K,2=V
  const bool vmode = (which == 2);

  const int srow = lane >> 3;
  const int ssw  = ((lane & 7) ^ srow) * 8;
  const unsigned short* gA = wq + (size_t)(o0 + 32 * w + srow) * CC + ssw;
  const unsigned short* gB = xT + ((size_t)b * NN + n0 + 32 * w + srow) * CC + ssw;

  f32x4 acc[4][4] = {};

  for (int c0 = 0; c0 < CC; c0 += 64) {
    __syncthreads();
#pragma unroll
    for (int L = 0; L < 4; ++L) {
      gld_lds16(gA + (size_t)(8 * L) * CC + c0, &As[(32 * w + 8 * L) * 64]);
      gld_lds16(gB + (size_t)(8 * L) * CC + c0, &Bs[(32 * w + 8 * L) * 64]);
    }
    __syncthreads();
    const unsigned short* Af = vmode ? Bs : As;
    const unsigned short* Bf = vmode ? As : Bs;
#pragma unroll
    for (int ks = 0; ks < 2; ++ks) {
      const int ph = ((ks * 4 + quad) ^ (l16 & 7)) * 8;
      bf16x8 af[4], bfr[4];
#pragma unroll
      for (int i = 0; i < 4; ++i) {
        af[i]  = *(const bf16x8*)&Af[(m_off + 16 * i + l16) * 64 + ph];
        bfr[i] = *(const bf16x8*)&Bf[(n_off + 16 * i + l16) * 64 + ph];
      }
#pragma unroll
      for (int i = 0; i < 4; ++i)
#pragma unroll
        for (int j = 0; j < 4; ++j)
          acc[i][j] = __builtin_amdgcn_mfma_f32_16x16x32_bf16(af[i], bfr[j], acc[i][j], 0, 0, 0);
    }
  }

  __syncthreads();
  const float sc = (which == 0) ? QSCALE : 1.0f;
#pragma unroll
  for (int i = 0; i < 4; ++i) {
#pragma unroll
    for (int j = 0; j < 4; ++j) {
      const int Drow = m_off + 16 * i + quad * 4;
      const int Dcol = n_off + 16 * j + l16;
      ushort4 p;
      p.x = f2bf(acc[i][j][0] * sc);
      p.y = f2bf(acc[i][j][1] * sc);
      p.z = f2bf(acc[i][j][2] * sc);
      p.w = f2bf(acc[i][j][3] * sc);
      *(ushort4*)&sm[Dcol * 136 + Drow] = p;
    }
  }
  __syncthreads();
  const int lrow = t >> 1;
  const int half = t & 1;
  const unsigned short* src = &sm[lrow * 136 + 64 * half];
  if (!vmode) {
    const int hh = ((o0 >> 6) & 7) + half;
    unsigned short* dst = (which == 0 ? qb : kb_) +
        ((size_t)(b * NH + hh) * NN + n0 + lrow) * HD;
#pragma unroll
    for (int i = 0; i < 8; ++i) *(uint4*)(dst + 8 * i) = *(const uint4*)(src + 8 * i);
  } else {
    const int hh = ((o0 + lrow) >> 6) & 7;
    const int d  = lrow & 63;
    unsigned short* dst = vt + ((size_t)(b * NH + hh) * HD + d) * NN + n0 + 64 * half;
#pragma unroll
    for (int i = 0; i < 8; ++i) *(uint4*)(dst + 8 * i) = *(const uint4*)(src + 8 * i);
  }
}

// ---------------------------------------------------------------------------
// attn_mfma v4: 32x32x16, no-max softmax, rho key-permutation (P pairs are
// the PV B-frag). NEW: pitch-72 DMA staging (9 16B-slots/row, slot 8 = pad,
// magic-div lane mapping) + 4*bit3(row) granule rotation -> conflict-free
// b128 reads. 64 queries/wave (2 Q-sets) halve K/V LDS reads per score.
// Block 128 (2 waves: wave0 DMAs K, wave1 DMAs V), grid (128 bh, 8 qtile).
// ---------------------------------------------------------------------------
__global__ __launch_bounds__(128) void attn_mfma(const unsigned short* __restrict__ Qg,
                                                 const unsigned short* __restrict__ Kg,
                                                 const unsigned short* __restrict__ Vtg,
                                                 unsigned short* __restrict__ attnB) {
  const int bh = blockIdx.x;     // id % 8 == bh % 8 -> XCD affinity
  const int b  = bh >> 3;
  const int h  = bh & 7;
  const int n0 = blockIdx.y * 128;
  const int t  = threadIdx.x;
  const int w    = t >> 6;       // 0 or 1
  const int lane = t & 63;
  const int l31  = lane & 31;
  const int hi   = lane >> 5;

  // K region: 64 rows x 72 shorts = 9216 B; V region same. Total 18432 B.
  __shared__ unsigned short sm[9216];
  unsigned short* Ks = sm;
  unsigned short* Vt = sm + 4608;

  // Q B-fragments for two query sets: B[n=query=l31][k=d=16c+8hi+j]
  const unsigned short* qbase = Qg + ((size_t)bh * NN + n0 + 64 * w) * HD + hi * 8;
  bf16x8 qf[2][4];
#pragma unroll
  for (int qs = 0; qs < 2; ++qs)
#pragma unroll
    for (int c = 0; c < 4; ++c)
      qf[qs][c] = *(const bf16x8*)(qbase + (size_t)(32 * qs + l31) * HD + 16 * c);

  // K A-row permutation rho (swap bits 2,3); granule rotations
  const int krow = (l31 & ~12) | ((l31 & 4) << 1) | ((l31 & 8) >> 1);
  const int fk   = ((krow >> 3) & 1) * 4;
  const int fv   = ((l31 >> 3) & 1) * 4;

  f32x16 oacc[2][2] = {};   // [qs][mt]: O^T D[m=d][n=query]
  float lacc[2] = {0.f, 0.f};

  // DMA staging precompute: wave0 -> K ([key][d]), wave1 -> V^T ([d][key]).
  // LDS slot idx = 64*s + lane -> row = idx/9 (magic 7282>>16, exact <576),
  // slotcol = idx%9; slotcol<8 holds global granule g = slotcol ^ f(row);
  // slotcol==8 is pad (fetch g=0, never read).
  int sOff[9];
#pragma unroll
  for (int s = 0; s < 9; ++s) {
    const int idx = 64 * s + lane;
    const int row = (idx * 7282) >> 16;
    const int scol = idx - 9 * row;
    const int fR  = ((row >> 3) & 1) * 4;
    const int g   = (scol < 8) ? (scol ^ fR) : 0;
    sOff[s] = (w == 0) ? (row * HD + g * 8) : (row * NN + g * 8);
  }
  const unsigned short* gsrc = (w == 0)
      ? (Kg + (size_t)bh * NN * HD)
      : (Vtg + (size_t)bh * HD * NN);
  const int tstep = (w == 0) ? 64 * HD : 64;
  unsigned short* sdst = (w == 0) ? Ks : Vt;

#pragma unroll 1
  for (int j0 = 0; j0 < NN; j0 += 64) {
    __syncthreads();
#pragma unroll
    for (int s = 0; s < 9; ++s) gld_lds16(gsrc + sOff[s], sdst + 512 * s);
    gsrc += tstep;
    __syncthreads();

#pragma unroll
    for (int kb = 0; kb < 2; ++kb) {
      // K fragments (shared by both q-sets): row rho(l31), pitch 72
      bf16x8 kf[4];
      const unsigned short* krp = Ks + (32 * kb + krow) * 72;
#pragma unroll
      for (int c = 0; c < 4; ++c)
        kf[c] = *(const bf16x8*)(krp + ((2 * c + hi) ^ fk) * 8);
      // V fragments (shared): row d = 32mt + l31
      bf16x8 vf[2][2];  // [g][mt]
#pragma unroll
      for (int mt = 0; mt < 2; ++mt) {
        const unsigned short* vrp = Vt + (32 * mt + l31) * 72;
#pragma unroll
        for (int g = 0; g < 2; ++g)
          vf[g][mt] = *(const bf16x8*)(vrp + ((4 * kb + 2 * g + hi) ^ fv) * 8);
      }
#pragma unroll
      for (int qs = 0; qs < 2; ++qs) {
        f32x16 st = {};
#pragma unroll
        for (int c = 0; c < 4; ++c)
          st = __builtin_amdgcn_mfma_f32_32x32x16_bf16(kf[c], qf[qs][c], st, 0, 0, 0);
        float e[16];
#pragma unroll
        for (int r = 0; r < 16; ++r) { e[r] = EXP2F(st[r]); lacc[qs] += e[r]; }
        unsigned P[8];
#pragma unroll
        for (int i = 0; i < 8; ++i) P[i] = pk2bf(e[2 * i], e[2 * i + 1]);
#pragma unroll
        for (int g = 0; g < 2; ++g) {
          union { unsigned u[4]; bf16x8 v; } cv;
          cv.u[0] = P[4 * g + 0]; cv.u[1] = P[4 * g + 1];
          cv.u[2] = P[4 * g + 2]; cv.u[3] = P[4 * g + 3];
#pragma unroll
          for (int mt = 0; mt < 2; ++mt)
            oacc[qs][mt] = __builtin_amdgcn_mfma_f32_32x32x16_bf16(
                vf[g][mt], cv.v, oacc[qs][mt], 0, 0, 0);
        }
      }
    }
  }

  float inv[2];
#pragma unroll
  for (int qs = 0; qs < 2; ++qs) {
    float l = lacc[qs];
    l += __shfl_xor(l, 32);
    inv[qs] = 1.0f / l;
  }

  // epilogue: wave-private LDS region (reuse staging), [query 0..63][d] pitch
  // 72, then 64B-per-lane global writes. One barrier: all waves done reading.
  __syncthreads();
  unsigned short* Es = sm + w * 4608;
#pragma unroll
  for (int qs = 0; qs < 2; ++qs) {
#pragma unroll
    for (int mt = 0; mt < 2; ++mt) {
#pragma unroll
      for (int rr = 0; rr < 4; ++rr) {
        const int d = 32 * mt + 8 * rr + 4 * hi;
        ushort4 p;
        p.x = f2bf(oacc[qs][mt][4 * rr + 0] * inv[qs]);
        p.y = f2bf(oacc[qs][mt][4 * rr + 1] * inv[qs]);
        p.z = f2bf(oacc[qs][mt][4 * rr + 2] * inv[qs]);
        p.w = f2bf(oacc[qs][mt][4 * rr + 3] * inv[qs]);
        *(ushort4*)&Es[(32 * qs + l31) * 72 + d] = p;
      }
    }
  }
  const int half = lane & 1;
#pragma unroll
  for (int p = 0; p < 2; ++p) {
    const int q = 32 * p + (lane >> 1);
    const unsigned short* src = &Es[q * 72 + 32 * half];
    unsigned short* gdst = attnB + ((size_t)b * NN + n0 + 64 * w + q) * CC +
                           h * HD + 32 * half;
#pragma unroll
    for (int i = 0; i < 4; ++i) *(uint4*)(gdst + 8 * i) = *(const uint4*)(src + 8 * i);
  }
}

// ---------------------------------------------------------------------------
// proj_mfma: out = w_proj @ attn + bias, bf16 MFMA, fp32 out [b][c][n].
// ---------------------------------------------------------------------------
__global__ __launch_bounds__(256) void proj_mfma(const unsigned short* __restrict__ wp,
                                                 const unsigned short* __restrict__ aB,
                                                 const float* __restrict__ bias,
                                                 float* __restrict__ out) {
  const int b  = blockIdx.z;
  const int o0 = blockIdx.y * 128;
  const int n0 = blockIdx.x * 128;
  const int t  = threadIdx.x;
  const int w    = t >> 6;
  const int lane = t & 63;
  const int quad = lane >> 4;
  const int l16  = lane & 15;
  const int m_off = (w >> 1) * 64;
  const int n_off = (w & 1) * 64;

  __shared__ unsigned short sm[16384];
  unsigned short* As = sm;
  unsigned short* Bs = sm + 8192;

  const int srow = lane >> 3;
  const int ssw  = ((lane & 7) ^ srow) * 8;
  const unsigned short* gA = wp + (size_t)(o0 + 32 * w + srow) * CC + ssw;
  const unsigned short* gB = aB + ((size_t)b * NN + n0 + 32 * w + srow) * CC + ssw;

  f32x4 acc[4][4] = {};

  for (int c0 = 0; c0 < CC; c0 += 64) {
    __syncthreads();
#pragma unroll
    for (int L = 0; L < 4; ++L) {
      gld_lds16(gA + (size_t)(8 * L) * CC + c0, &As[(32 * w + 8 * L) * 64]);
      gld_lds16(gB + (size_t)(8 * L) * CC + c0, &Bs[(32 * w + 8 * L) * 64]);
    }
    __syncthreads();
#pragma unroll
    for (int ks = 0; ks < 2; ++ks) {
      const int ph = ((ks * 4 + quad) ^ (l16 & 7)) * 8;
      bf16x8 af[4], bfr[4];
#pragma unroll
      for (int i = 0; i < 4; ++i) {
        af[i]  = *(const bf16x8*)&As[(m_off + 16 * i + l16) * 64 + ph];
        bfr[i] = *(const bf16x8*)&Bs[(n_off + 16 * i + l16) * 64 + ph];
      }
#pragma unroll
      for (int i = 0; i < 4; ++i)
#pragma unroll
        for (int j = 0; j < 4; ++j)
          acc[i][j] = __builtin_amdgcn_mfma_f32_16x16x32_bf16(af[i], bfr[j], acc[i][j], 0, 0, 0);
    }
  }

#pragma unroll
  for (int i = 0; i < 4; ++i) {
#pragma unroll
    for (int r = 0; r < 4; ++r) {
      const int o = o0 + m_off + 16 * i + quad * 4 + r;
      const float bv = bias[o];
      float* orow = out + ((size_t)b * CC + o) * NN + n0 + n_off;
#pragma unroll
      for (int j = 0; j < 4; ++j)
        orow[16 * j + l16] = acc[i][j][r] + bv;
    }
  }
}

// ---------------------------------------------------------------------------
extern "C" void kernel_launch(void* const* d_in, const int* in_sizes, int n_in,
                              void* d_out, int out_size, void* d_ws, size_t ws_size,
                              hipStream_t stream) {
  const float* x      = (const float*)d_in[0];
  const float* w_qkv  = (const float*)d_in[1];
  const float* w_proj = (const float*)d_in[2];
  const float* b_proj = (const float*)d_in[3];
  char* wsb  = (char*)d_ws;
  float* out = (float*)d_out;

  unsigned short* xT  = (unsigned short*)(wsb + XT_OFF);
  unsigned short* wq  = (unsigned short*)(wsb + WQ_OFF);
  unsigned short* wp  = (unsigned short*)(wsb + WP_OFF);
  unsigned short* qb  = (unsigned short*)(wsb + QB_OFF);
  unsigned short* kb_ = (unsigned short*)(wsb + KB_OFF);
  unsigned short* vt  = (unsigned short*)(wsb + VT_OFF);
  unsigned short* aB  = (unsigned short*)(wsb + AB_OFF);

  prep_w<<<512, 256, 0, stream>>>(w_qkv, w_proj, wq, wp);
  prep_xT<<<dim3(16, 8, BB), 256, 0, stream>>>(x, xT);
  qkv_mfma<<<dim3(8, 12, BB), 256, 0, stream>>>(wq, xT, qb, kb_, vt);
  attn_mfma<<<dim3(BB * NH, NN / 128), 128, 0, stream>>>(qb, kb_, vt, aB);
  proj_mfma<<<dim3(8, 4, BB), 256, 0, stream>>>(wp, aB, b_proj, out);
}

// Round 7
// 210.485 us; speedup vs baseline: 1.0120x; 1.0120x over previous
//
#include <hip/hip_runtime.h>
#include <hip/hip_bf16.h>
#include <math.h>

#define BB 16
#define CC 512
#define NH 8
#define HD 64
#define NN 1024   // H*W
#define THREEC 1536

// Q pre-scale: (1/sqrt(64)) * log2(e)  -> softmax via raw v_exp_f32 (2^x)
#define QSCALE 0.18033688f

typedef __attribute__((ext_vector_type(8))) short bf16x8;
typedef __attribute__((ext_vector_type(4))) float f32x4;
typedef __attribute__((ext_vector_type(16))) float f32x16;

#if __has_builtin(__builtin_amdgcn_exp2f)
#define EXP2F __builtin_amdgcn_exp2f
#else
#define EXP2F exp2f
#endif

// workspace byte offsets
#define XT_OFF 0u           // bf16 x^T [b][n][c]          (16.78 MB)
#define WQ_OFF 16777216u    // bf16 w_qkv [1536][512]      (1.57 MB)
#define WP_OFF 18350080u    // bf16 w_proj [512][512]      (0.52 MB)
#define QB_OFF 18874368u    // bf16 Q (scaled QSCALE) [bh][n][d]
#define KB_OFF 35651584u    // bf16 K [bh][n][d]
#define VT_OFF 52428800u    // bf16 V^T [bh][d][n]
#define AB_OFF 69206016u    // bf16 attn-out [b][n][c]
// end 85983232 (82 MiB)

static __device__ inline unsigned short f2bf(float f) {
  union { float f; unsigned u; } v; v.f = f;
  unsigned r = v.u + 0x7fffu + ((v.u >> 16) & 1u);
  return (unsigned short)(r >> 16);
}

// pack two f32 -> two bf16 in a u32 (lo = a, hi = b)
static __device__ inline unsigned pk2bf(float a, float b) {
#if defined(__AMDGCN__) && __has_builtin(__builtin_amdgcn_cvt_pk_bf16_f32)
  typedef __attribute__((ext_vector_type(2))) __bf16 bfp2;
  union { bfp2 v; unsigned u; } z;
  z.v = __builtin_amdgcn_cvt_pk_bf16_f32(a, b);
  return z.u;
#else
  return (unsigned)f2bf(a) | ((unsigned)f2bf(b) << 16);
#endif
}

static __device__ inline void gld_lds16(const unsigned short* g, unsigned short* l) {
  __builtin_amdgcn_global_load_lds(
      (const __attribute__((address_space(1))) unsigned int*)g,
      (__attribute__((address_space(3))) unsigned int*)l, 16, 0, 0);
}

// ---------------------------------------------------------------------------
// prep_w: convert w_qkv (786432) + w_proj (262144) fp32 -> bf16
// ---------------------------------------------------------------------------
__global__ __launch_bounds__(256) void prep_w(const float* __restrict__ wqkv,
                                              const float* __restrict__ wproj,
                                              unsigned short* __restrict__ dq,
                                              unsigned short* __restrict__ dp) {
  const size_t i8 = ((size_t)blockIdx.x * 256 + threadIdx.x) * 8;
  const float* src;
  unsigned short* dst;
  if (i8 < 786432u) { src = wqkv + i8; dst = dq + i8; }
  else              { src = wproj + (i8 - 786432u); dst = dp + (i8 - 786432u); }
  float4 a = *(const float4*)src;
  float4 b = *(const float4*)(src + 4);
  unsigned short pk[8] = {f2bf(a.x), f2bf(a.y), f2bf(a.z), f2bf(a.w),
                          f2bf(b.x), f2bf(b.y), f2bf(b.z), f2bf(b.w)};
  *(uint4*)dst = *(const uint4*)pk;
}

// ---------------------------------------------------------------------------
// prep_xT: x [b][c][n] fp32 -> xT [b][n][c] bf16. 64x64 LDS tile transpose.
// ---------------------------------------------------------------------------
__global__ __launch_bounds__(256) void prep_xT(const float* __restrict__ x,
                                               unsigned short* __restrict__ xT) {
  const int b  = blockIdx.z;
  const int c0 = blockIdx.y * 64;
  const int n0 = blockIdx.x * 64;
  __shared__ float tile[64][65];
  const int t  = threadIdx.x;
  const int cl = t >> 4, n4 = (t & 15) * 4;
#pragma unroll
  for (int r = 0; r < 4; ++r) {
    float4 v = *(const float4*)&x[((size_t)b * CC + c0 + cl + 16 * r) * NN + n0 + n4];
    *(float4*)&tile[cl + 16 * r][n4] = v;
  }
  __syncthreads();
  const int nl = t >> 4, c4 = (t & 15) * 4;
#pragma unroll
  for (int r = 0; r < 4; ++r) {
    ushort4 p;
    p.x = f2bf(tile[c4 + 0][nl + 16 * r]);
    p.y = f2bf(tile[c4 + 1][nl + 16 * r]);
    p.z = f2bf(tile[c4 + 2][nl + 16 * r]);
    p.w = f2bf(tile[c4 + 3][nl + 16 * r]);
    *(ushort4*)&xT[((size_t)b * NN + n0 + nl + 16 * r) * CC + c0 + c4] = p;
  }
}

// ---------------------------------------------------------------------------
// qkv_mfma: [1536x512] @ [512x1024] per batch, bf16 MFMA, 128x128 tile BK=64.
// ---------------------------------------------------------------------------
__global__ __launch_bounds__(256) void qkv_mfma(const unsigned short* __restrict__ wq,
                                                const unsigned short* __restrict__ xT,
                                                unsigned short* __restrict__ qb,
                                                unsigned short* __restrict__ kb_,
                                                unsigned short* __restrict__ vt) {
  const int b  = blockIdx.z;
  const int o0 = blockIdx.y * 128;
  const int n0 = blockIdx.x * 128;
  const int t  = threadIdx.x;
  const int w    = t >> 6;
  const int lane = t & 63;
  const int quad = lane >> 4;
  const int l16  = lane & 15;
  const int m_off = (w >> 1) * 64;
  const int n_off = (w & 1) * 64;

  __shared__ unsigned short sm[17408];
  unsigned short* As = sm;
  unsigned short* Bs = sm + 8192;

  const int which = o0 >> 9;       // 0=Q,1=K,2=V
  const bool vmode = (which == 2);

  const int srow = lane >> 3;
  const int ssw  = ((lane & 7) ^ srow) * 8;
  const unsigned short* gA = wq + (size_t)(o0 + 32 * w + srow) * CC + ssw;
  const unsigned short* gB = xT + ((size_t)b * NN + n0 + 32 * w + srow) * CC + ssw;

  f32x4 acc[4][4] = {};

  for (int c0 = 0; c0 < CC; c0 += 64) {
    __syncthreads();
#pragma unroll
    for (int L = 0; L < 4; ++L) {
      gld_lds16(gA + (size_t)(8 * L) * CC + c0, &As[(32 * w + 8 * L) * 64]);
      gld_lds16(gB + (size_t)(8 * L) * CC + c0, &Bs[(32 * w + 8 * L) * 64]);
    }
    __syncthreads();
    const unsigned short* Af = vmode ? Bs : As;
    const unsigned short* Bf = vmode ? As : Bs;
#pragma unroll
    for (int ks = 0; ks < 2; ++ks) {
      const int ph = ((ks * 4 + quad) ^ (l16 & 7)) * 8;
      bf16x8 af[4], bfr[4];
#pragma unroll
      for (int i = 0; i < 4; ++i) {
        af[i]  = *(const bf16x8*)&Af[(m_off + 16 * i + l16) * 64 + ph];
        bfr[i] = *(const bf16x8*)&Bf[(n_off + 16 * i + l16) * 64 + ph];
      }
#pragma unroll
      for (int i = 0; i < 4; ++i)
#pragma unroll
        for (int j = 0; j < 4; ++j)
          acc[i][j] = __builtin_amdgcn_mfma_f32_16x16x32_bf16(af[i], bfr[j], acc[i][j], 0, 0, 0);
    }
  }

  __syncthreads();
  const float sc = (which == 0) ? QSCALE : 1.0f;
#pragma unroll
  for (int i = 0; i < 4; ++i) {
#pragma unroll
    for (int j = 0; j < 4; ++j) {
      const int Drow = m_off + 16 * i + quad * 4;
      const int Dcol = n_off + 16 * j + l16;
      ushort4 p;
      p.x = f2bf(acc[i][j][0] * sc);
      p.y = f2bf(acc[i][j][1] * sc);
      p.z = f2bf(acc[i][j][2] * sc);
      p.w = f2bf(acc[i][j][3] * sc);
      *(ushort4*)&sm[Dcol * 136 + Drow] = p;
    }
  }
  __syncthreads();
  const int lrow = t >> 1;
  const int half = t & 1;
  const unsigned short* src = &sm[lrow * 136 + 64 * half];
  if (!vmode) {
    const int hh = ((o0 >> 6) & 7) + half;
    unsigned short* dst = (which == 0 ? qb : kb_) +
        ((size_t)(b * NH + hh) * NN + n0 + lrow) * HD;
#pragma unroll
    for (int i = 0; i < 8; ++i) *(uint4*)(dst + 8 * i) = *(const uint4*)(src + 8 * i);
  } else {
    const int hh = ((o0 + lrow) >> 6) & 7;
    const int d  = lrow & 63;
    unsigned short* dst = vt + ((size_t)(b * NH + hh) * HD + d) * NN + n0 + 64 * half;
#pragma unroll
    for (int i = 0; i < 8; ++i) *(uint4*)(dst + 8 * i) = *(const uint4*)(src + 8 * i);
  }
}

// ---------------------------------------------------------------------------
// attn_mfma v5: 32x32x16, no-max softmax, rho key-permutation, pitch-72
// conflict-mitigated staging — NOW: 4 waves x 64 queries (256 q/block) and
// DOUBLE-BUFFERED DMA staging: tile j+1's global_load_lds issues right after
// the barrier, compute on tile j covers its latency, so the pre-barrier
// vmcnt drain is cheap. Waves 0,1 stage K; waves 2,3 stage V.
// LDS: 2 buffers x (K 9216B + V 9216B) = 36864B.
// grid (128 bh, 4 qtile), block 256.
// ---------------------------------------------------------------------------
__global__ __launch_bounds__(256) void attn_mfma(const unsigned short* __restrict__ Qg,
                                                 const unsigned short* __restrict__ Kg,
                                                 const unsigned short* __restrict__ Vtg,
                                                 unsigned short* __restrict__ attnB) {
  const int bh = blockIdx.x;     // id % 8 == bh % 8 -> XCD affinity
  const int b  = bh >> 3;
  const int h  = bh & 7;
  const int n0 = blockIdx.y * 256;
  const int t  = threadIdx.x;
  const int w    = t >> 6;       // 0..3
  const int lane = t & 63;
  const int l31  = lane & 31;
  const int hi   = lane >> 5;

  // buffer = K(4608 shorts) + V(4608); two buffers
  __shared__ unsigned short sm[18432];

  // Q B-fragments for two query sets: B[n=query=l31][k=d=16c+8hi+j]
  const unsigned short* qbase = Qg + ((size_t)bh * NN + n0 + 64 * w) * HD + hi * 8;
  bf16x8 qf[2][4];
#pragma unroll
  for (int qs = 0; qs < 2; ++qs)
#pragma unroll
    for (int c = 0; c < 4; ++c)
      qf[qs][c] = *(const bf16x8*)(qbase + (size_t)(32 * qs + l31) * HD + 16 * c);

  // K A-row permutation rho (swap bits 2,3); granule rotations
  const int krow = (l31 & ~12) | ((l31 & 4) << 1) | ((l31 & 8) >> 1);
  const int fk   = ((krow >> 3) & 1) * 4;
  const int fv   = ((l31 >> 3) & 1) * 4;

  f32x16 oacc[2][2] = {};   // [qs][mt]: O^T D[m=d][n=query]
  float lacc[2] = {0.f, 0.f};

  // DMA staging: waves 0,1 -> K [key][d]; waves 2,3 -> V^T [d][key].
  // 576 granules per region; pair-lane p = (w&1)*64+lane; granule idx =
  // 128*s + p; s=0..3 all, s=4 only (w&1)==0 (idx 512..575).
  // idx -> row = idx/9 (magic 7282>>16), scol = idx%9; scol<8 holds global
  // granule g = scol ^ (4*bit3(row)); scol==8 = pad (fetch g=0, never read).
  const bool kv = (w >= 2);
  int sOff[5];
#pragma unroll
  for (int s = 0; s < 5; ++s) {
    const int idx = 128 * s + (w & 1) * 64 + lane;
    const int row = (idx * 7282) >> 16;
    const int scol = idx - 9 * row;
    const int fR  = ((row >> 3) & 1) * 4;
    const int g   = (scol < 8) ? (scol ^ fR) : 0;
    sOff[s] = kv ? (row * NN + g * 8) : (row * HD + g * 8);
  }
  const unsigned short* gbase = kv ? (Vtg + (size_t)bh * HD * NN)
                                   : (Kg + (size_t)bh * NN * HD);
  const int gstep = kv ? 64 : 64 * HD;           // per 64-key tile
  unsigned short* lbase = sm + (kv ? 4608 : 0) + ((w & 1) * 64) * 8;

  // prologue: stage tile 0 into buffer 0
#pragma unroll
  for (int s = 0; s < 5; ++s)
    if (s < 4 || (w & 1) == 0) gld_lds16(gbase + sOff[s], lbase + 1024 * s);

#pragma unroll 1
  for (int jt = 0; jt < 16; ++jt) {
    __syncthreads();   // drains DMA for buf[jt&1]; frees buf[(jt+1)&1]
    if (jt < 15) {
      const unsigned short* gn = gbase + (size_t)(jt + 1) * gstep;
      unsigned short* ln = lbase + ((jt + 1) & 1) * 9216;
#pragma unroll
      for (int s = 0; s < 5; ++s)
        if (s < 4 || (w & 1) == 0) gld_lds16(gn + sOff[s], ln + 1024 * s);
    }
    const unsigned short* Ks = sm + (jt & 1) * 9216;
    const unsigned short* Vt = Ks + 4608;

#pragma unroll
    for (int kb = 0; kb < 2; ++kb) {
      // K fragments (shared by both q-sets): row rho(l31), pitch 72
      bf16x8 kf[4];
      const unsigned short* krp = Ks + (32 * kb + krow) * 72;
#pragma unroll
      for (int c = 0; c < 4; ++c)
        kf[c] = *(const bf16x8*)(krp + ((2 * c + hi) ^ fk) * 8);
      // V fragments (shared): row d = 32mt + l31
      bf16x8 vf[2][2];  // [g][mt]
#pragma unroll
      for (int mt = 0; mt < 2; ++mt) {
        const unsigned short* vrp = Vt + (32 * mt + l31) * 72;
#pragma unroll
        for (int g = 0; g < 2; ++g)
          vf[g][mt] = *(const bf16x8*)(vrp + ((4 * kb + 2 * g + hi) ^ fv) * 8);
      }
#pragma unroll
      for (int qs = 0; qs < 2; ++qs) {
        f32x16 st = {};
#pragma unroll
        for (int c = 0; c < 4; ++c)
          st = __builtin_amdgcn_mfma_f32_32x32x16_bf16(kf[c], qf[qs][c], st, 0, 0, 0);
        float e[16];
#pragma unroll
        for (int r = 0; r < 16; ++r) { e[r] = EXP2F(st[r]); lacc[qs] += e[r]; }
        unsigned P[8];
#pragma unroll
        for (int i = 0; i < 8; ++i) P[i] = pk2bf(e[2 * i], e[2 * i + 1]);
#pragma unroll
        for (int g = 0; g < 2; ++g) {
          union { unsigned u[4]; bf16x8 v; } cv;
          cv.u[0] = P[4 * g + 0]; cv.u[1] = P[4 * g + 1];
          cv.u[2] = P[4 * g + 2]; cv.u[3] = P[4 * g + 3];
#pragma unroll
          for (int mt = 0; mt < 2; ++mt)
            oacc[qs][mt] = __builtin_amdgcn_mfma_f32_32x32x16_bf16(
                vf[g][mt], cv.v, oacc[qs][mt], 0, 0, 0);
        }
      }
    }
  }

  float inv[2];
#pragma unroll
  for (int qs = 0; qs < 2; ++qs) {
    float l = lacc[qs];
    l += __shfl_xor(l, 32);
    inv[qs] = 1.0f / l;
  }

  // epilogue: wave-private LDS region, [query 0..63][d] pitch 72,
  // then 64B-per-lane global writes.
  __syncthreads();
  unsigned short* Es = sm + w * 4608;
#pragma unroll
  for (int qs = 0; qs < 2; ++qs) {
#pragma unroll
    for (int mt = 0; mt < 2; ++mt) {
#pragma unroll
      for (int rr = 0; rr < 4; ++rr) {
        const int d = 32 * mt + 8 * rr + 4 * hi;
        ushort4 p;
        p.x = f2bf(oacc[qs][mt][4 * rr + 0] * inv[qs]);
        p.y = f2bf(oacc[qs][mt][4 * rr + 1] * inv[qs]);
        p.z = f2bf(oacc[qs][mt][4 * rr + 2] * inv[qs]);
        p.w = f2bf(oacc[qs][mt][4 * rr + 3] * inv[qs]);
        *(ushort4*)&Es[(32 * qs + l31) * 72 + d] = p;
      }
    }
  }
  const int half = lane & 1;
#pragma unroll
  for (int p = 0; p < 2; ++p) {
    const int q = 32 * p + (lane >> 1);
    const unsigned short* src = &Es[q * 72 + 32 * half];
    unsigned short* gdst = attnB + ((size_t)b * NN + n0 + 64 * w + q) * CC +
                           h * HD + 32 * half;
#pragma unroll
    for (int i = 0; i < 4; ++i) *(uint4*)(gdst + 8 * i) = *(const uint4*)(src + 8 * i);
  }
}

// ---------------------------------------------------------------------------
// proj_mfma: out = w_proj @ attn + bias, bf16 MFMA, fp32 out [b][c][n].
// ---------------------------------------------------------------------------
__global__ __launch_bounds__(256) void proj_mfma(const unsigned short* __restrict__ wp,
                                                 const unsigned short* __restrict__ aB,
                                                 const float* __restrict__ bias,
                                                 float* __restrict__ out) {
  const int b  = blockIdx.z;
  const int o0 = blockIdx.y * 128;
  const int n0 = blockIdx.x * 128;
  const int t  = threadIdx.x;
  const int w    = t >> 6;
  const int lane = t & 63;
  const int quad = lane >> 4;
  const int l16  = lane & 15;
  const int m_off = (w >> 1) * 64;
  const int n_off = (w & 1) * 64;

  __shared__ unsigned short sm[16384];
  unsigned short* As = sm;
  unsigned short* Bs = sm + 8192;

  const int srow = lane >> 3;
  const int ssw  = ((lane & 7) ^ srow) * 8;
  const unsigned short* gA = wp + (size_t)(o0 + 32 * w + srow) * CC + ssw;
  const unsigned short* gB = aB + ((size_t)b * NN + n0 + 32 * w + srow) * CC + ssw;

  f32x4 acc[4][4] = {};

  for (int c0 = 0; c0 < CC; c0 += 64) {
    __syncthreads();
#pragma unroll
    for (int L = 0; L < 4; ++L) {
      gld_lds16(gA + (size_t)(8 * L) * CC + c0, &As[(32 * w + 8 * L) * 64]);
      gld_lds16(gB + (size_t)(8 * L) * CC + c0, &Bs[(32 * w + 8 * L) * 64]);
    }
    __syncthreads();
#pragma unroll
    for (int ks = 0; ks < 2; ++ks) {
      const int ph = ((ks * 4 + quad) ^ (l16 & 7)) * 8;
      bf16x8 af[4], bfr[4];
#pragma unroll
      for (int i = 0; i < 4; ++i) {
        af[i]  = *(const bf16x8*)&As[(m_off + 16 * i + l16) * 64 + ph];
        bfr[i] = *(const bf16x8*)&Bs[(n_off + 16 * i + l16) * 64 + ph];
      }
#pragma unroll
      for (int i = 0; i < 4; ++i)
#pragma unroll
        for (int j = 0; j < 4; ++j)
          acc[i][j] = __builtin_amdgcn_mfma_f32_16x16x32_bf16(af[i], bfr[j], acc[i][j], 0, 0, 0);
    }
  }

#pragma unroll
  for (int i = 0; i < 4; ++i) {
#pragma unroll
    for (int r = 0; r < 4; ++r) {
      const int o = o0 + m_off + 16 * i + quad * 4 + r;
      const float bv = bias[o];
      float* orow = out + ((size_t)b * CC + o) * NN + n0 + n_off;
#pragma unroll
      for (int j = 0; j < 4; ++j)
        orow[16 * j + l16] = acc[i][j][r] + bv;
    }
  }
}

// ---------------------------------------------------------------------------
extern "C" void kernel_launch(void* const* d_in, const int* in_sizes, int n_in,
                              void* d_out, int out_size, void* d_ws, size_t ws_size,
                              hipStream_t stream) {
  const float* x      = (const float*)d_in[0];
  const float* w_qkv  = (const float*)d_in[1];
  const float* w_proj = (const float*)d_in[2];
  const float* b_proj = (const float*)d_in[3];
  char* wsb  = (char*)d_ws;
  float* out = (float*)d_out;

  unsigned short* xT  = (unsigned short*)(wsb + XT_OFF);
  unsigned short* wq  = (unsigned short*)(wsb + WQ_OFF);
  unsigned short* wp  = (unsigned short*)(wsb + WP_OFF);
  unsigned short* qb  = (unsigned short*)(wsb + QB_OFF);
  unsigned short* kb_ = (unsigned short*)(wsb + KB_OFF);
  unsigned short* vt  = (unsigned short*)(wsb + VT_OFF);
  unsigned short* aB  = (unsigned short*)(wsb + AB_OFF);

  prep_w<<<512, 256, 0, stream>>>(w_qkv, w_proj, wq, wp);
  prep_xT<<<dim3(16, 8, BB), 256, 0, stream>>>(x, xT);
  qkv_mfma<<<dim3(8, 12, BB), 256, 0, stream>>>(wq, xT, qb, kb_, vt);
  attn_mfma<<<dim3(BB * NH, NN / 256), 256, 0, stream>>>(qb, kb_, vt, aB);
  proj_mfma<<<dim3(8, 4, BB), 256, 0, stream>>>(wp, aB, b_proj, out);
}